// Round 1
// baseline (566.158 us; speedup 1.0000x reference)
//
#include <hip/hip_runtime.h>

// LatticeSuperpixel: B=8, C=20, H=W=512, 32x32 seeds, 16x16 cells, 4 levels.
//
// R1 design:
//  - Seeds + seed-norms are block-uniform -> loaded via the SCALAR path
//    (s_load into SGPRs; v_fmac with SGPR operand). No LDS staging of seeds,
//    no per-thread b128 re-reads, one less barrier in k_iter, NO LDS at all
//    in k_final.
//  - Seed norms precomputed once per seed update (k_seed_init / k_divz)
//    instead of per-block.
//  - k_iter phase 2 register-tiled on a single wave: thread=(cg<7, s<8),
//    acc[3ch][9off] in registers; LDS read instrs 288 -> 96 per block.
//    Denominator via a ones-row (row 20) of the x tile.
//  - k_divz fuses divide + numer/denom re-zero + norm; only one memset total.
#define NB 8
#define NC 20
#define NH 512
#define NW 512
#define NS 1024           // 32*32 seeds
#define HW (NH * NW)
#define SEEDS_ELEMS (NB * NS * NC)   // 163840
#define DENOM_ELEMS (NB * NS)        // 8192
#define EPSF 1e-8f

static constexpr int DYO[9] = {-1, -1, -1, 0, 0, 0, 1, 1, 1};
static constexpr int DXO[9] = {-1, 0, 1, -1, 0, 1, -1, 0, 1};

__device__ __forceinline__ int clampi(int v, int lo, int hi) {
    return v < lo ? lo : (v > hi ? hi : v);
}

// ---------------------------------------------------------------------------
// Kernel 1: seed init = mean over each 16x16 patch, per channel + seed norm.
// ---------------------------------------------------------------------------
__global__ __launch_bounds__(160) void k_seed_init(const float* __restrict__ x,
                                                   float* __restrict__ seeds,
                                                   float* __restrict__ snorm) {
    __shared__ float sm[NC];
    const int tt = threadIdx.x;           // < 160
    const int cell = blockIdx.x;
    const int b = blockIdx.y;
    const int cy = cell >> 5, cx = cell & 31;
    const int c = tt >> 3, s = tt & 7;

    const float* xb = x + (size_t)b * (NC * HW) + (size_t)c * HW
                        + (size_t)(cy << 4) * NW + (cx << 4);
    float acc = 0.f;
#pragma unroll
    for (int k = 0; k < 8; ++k) {
        const int row = (k << 1) + (s >> 2);
        const int col = (s & 3) << 2;
        const float4 v = *reinterpret_cast<const float4*>(xb + row * NW + col);
        acc += v.x + v.y + v.z + v.w;
    }
    acc += __shfl_xor(acc, 1, 64);
    acc += __shfl_xor(acc, 2, 64);
    acc += __shfl_xor(acc, 4, 64);
    if (s == 0) {
        const float mv = acc * (1.0f / 256.0f);
        seeds[((size_t)(b << 10) + cell) * NC + c] = mv;
        sm[c] = mv;
    }
    __syncthreads();
    if (tt == 0) {
        float n = 0.f;
#pragma unroll
        for (int cc = 0; cc < NC; ++cc) n += sm[cc] * sm[cc];
        snorm[(b << 10) + cell] = n;
    }
}

// ---------------------------------------------------------------------------
// Kernel 2: one assignment iteration + seed-update accumulation.
// Phase 1: 256 thr = 1 pixel: dist vs 9 seeds (seeds via SGPR scalar loads),
//          softmax -> qs.
// Phase 2: ONE wave, thread=(cg in 0..6, s in 0..7): channels {3cg..3cg+2}
//          (c==20 is the ones-row -> denom), all 9 offsets in acc[3][9].
//          96 b128 LDS reads/block (was 288 wave-instrs), fold s via shfl,
//          189 atomics/block (unchanged).
// ---------------------------------------------------------------------------
__global__ __launch_bounds__(256, 4) void k_iter(const float* __restrict__ x,
                                                 const float* __restrict__ seeds,
                                                 const float* __restrict__ snorm,
                                                 float* __restrict__ numer,
                                                 float* __restrict__ denom) {
    __shared__ __align__(16) float xs[21 * 256];  // rows 0..19 = x, row 20 = ones
    __shared__ __align__(16) float qs[9 * 256];

    const int t = threadIdx.x;
    const int cell = blockIdx.x;
    const int b = blockIdx.y;
    const int cy = cell >> 5, cx = cell & 31;

    // block-uniform neighbor-seed indices -> force SGPR
    int nidx[9];
#pragma unroll
    for (int o = 0; o < 9; ++o) {
        const int ny = clampi(cy + DYO[o], 0, 31);
        const int nx = clampi(cx + DXO[o], 0, 31);
        nidx[o] = __builtin_amdgcn_readfirstlane((b << 10) + (ny << 5) + nx);
    }

    // ---- stage x tile into LDS (channel-major, pixel-linear, stride 256) ----
    const float* xb = x + (size_t)b * (NC * HW) + (size_t)(cy << 4) * NW + (cx << 4);
#pragma unroll
    for (int j = 0; j < 5; ++j) {
        const int Lq = (j << 8) + t;          // linear quad id: c*64 + qd
        const int c = Lq >> 6, qd = Lq & 63;
        const float4 v = *reinterpret_cast<const float4*>(
            xb + (size_t)c * HW + (qd >> 2) * NW + ((qd & 3) << 2));
        *reinterpret_cast<float4*>(&xs[(c << 8) + (qd << 2)]) = v;
    }
    xs[(20 << 8) + t] = 1.0f;                 // ones-row for denominator
    __syncthreads();

    // ---- phase 1: per-pixel distances (seeds from scalar path) + softmax ----
    float xv[NC];
#pragma unroll
    for (int c = 0; c < NC; ++c) xv[c] = xs[(c << 8) + t];

    float d[9];
#pragma unroll
    for (int o = 0; o < 9; ++o) {
        const float* sp = seeds + (size_t)nidx[o] * NC;  // uniform -> s_load
        float ip = 0.f;
#pragma unroll
        for (int c = 0; c < NC; ++c) ip += xv[c] * sp[c];
        d[o] = snorm[nidx[o]] - 2.0f * ip;
    }
    float m = d[0];
#pragma unroll
    for (int o = 1; o < 9; ++o) m = fminf(m, d[o]);
    float w[9];
    float wsum = 0.f;
#pragma unroll
    for (int o = 0; o < 9; ++o) {
        w[o] = __expf(m - d[o]);
        wsum += w[o];
    }
    const float inv = 1.0f / wsum;
#pragma unroll
    for (int o = 0; o < 9; ++o) qs[(o << 8) + t] = w[o] * inv;
    __syncthreads();

    // ---- phase 2: single-wave register-tiled 21x9 reduction ----
    if (t < 56) {
        const int cg = t >> 3, s = t & 7;
        const int r0 = cg * 3;
        float acc[3][9];
#pragma unroll
        for (int j = 0; j < 3; ++j)
#pragma unroll
            for (int o = 0; o < 9; ++o) acc[j][o] = 0.f;

#pragma unroll
        for (int k = 0; k < 8; ++k) {
            const int qd4 = ((k << 3) + s) << 2;
            const float4 x0 = *reinterpret_cast<const float4*>(&xs[((r0 + 0) << 8) + qd4]);
            const float4 x1 = *reinterpret_cast<const float4*>(&xs[((r0 + 1) << 8) + qd4]);
            const float4 x2 = *reinterpret_cast<const float4*>(&xs[((r0 + 2) << 8) + qd4]);
#pragma unroll
            for (int o = 0; o < 9; ++o) {
                const float4 q4 = *reinterpret_cast<const float4*>(&qs[(o << 8) + qd4]);
                acc[0][o] += q4.x * x0.x + q4.y * x0.y + q4.z * x0.z + q4.w * x0.w;
                acc[1][o] += q4.x * x1.x + q4.y * x1.y + q4.z * x1.z + q4.w * x1.w;
                acc[2][o] += q4.x * x2.x + q4.y * x2.y + q4.z * x2.z + q4.w * x2.w;
            }
        }
        // fold the 8 strips (s = lane bits 0..2)
#pragma unroll
        for (int j = 0; j < 3; ++j)
#pragma unroll
            for (int o = 0; o < 9; ++o) {
                acc[j][o] += __shfl_xor(acc[j][o], 1, 64);
                acc[j][o] += __shfl_xor(acc[j][o], 2, 64);
                acc[j][o] += __shfl_xor(acc[j][o], 4, 64);
            }
        if (s == 0) {
#pragma unroll
            for (int o = 0; o < 9; ++o) {
                const size_t sb = (size_t)nidx[o];
#pragma unroll
                for (int j = 0; j < 3; ++j) {
                    const int c = r0 + j;
                    if (c < NC) atomicAdd(&numer[sb * NC + c], acc[j][o]);
                    else        atomicAdd(&denom[sb], acc[j][o]);
                }
            }
        }
    }
}

// ---------------------------------------------------------------------------
// Kernel 3: seeds = numer/(denom+eps), re-zero numer/denom, seed norms.
// 160 thr = 8 seeds x 20 channels per block; grid = 1024.
// ---------------------------------------------------------------------------
__global__ __launch_bounds__(160) void k_divz(float* __restrict__ seeds,
                                              float* __restrict__ snorm,
                                              float* __restrict__ numer,
                                              float* __restrict__ denom) {
    __shared__ float sq[160];
    const int t = threadIdx.x;
    const int gidx = blockIdx.x * 160 + t;
    const int sid = blockIdx.x * 8 + t / 20;
    const float v = numer[gidx] / (denom[sid] + EPSF);
    seeds[gidx] = v;
    numer[gidx] = 0.f;
    sq[t] = v * v;
    __syncthreads();
    if (t < 8) {
        const int ss = blockIdx.x * 8 + t;
        float n = 0.f;
#pragma unroll
        for (int c = 0; c < NC; ++c) n += sq[t * 20 + c];
        snorm[ss] = n;
        denom[ss] = 0.f;
    }
}

// ---------------------------------------------------------------------------
// Kernel 4: final assignment pass -> write Q (B, 9, H, W). No LDS, no barriers.
// ---------------------------------------------------------------------------
__global__ __launch_bounds__(256) void k_final(const float* __restrict__ x,
                                               const float* __restrict__ seeds,
                                               const float* __restrict__ snorm,
                                               float* __restrict__ out) {
    const int t = threadIdx.x;
    const int cell = blockIdx.x;
    const int b = blockIdx.y;
    const int cy = cell >> 5, cx = cell & 31;

    const int py = (cy << 4) + (t >> 4);
    const int px = (cx << 4) + (t & 15);
    const float* xp = x + (size_t)b * (NC * HW) + (size_t)py * NW + px;
    float xv[NC];
#pragma unroll
    for (int c = 0; c < NC; ++c) xv[c] = xp[(size_t)c * HW];

    float d[9];
#pragma unroll
    for (int o = 0; o < 9; ++o) {
        const int ny = clampi(cy + DYO[o], 0, 31);
        const int nx = clampi(cx + DXO[o], 0, 31);
        const int si = __builtin_amdgcn_readfirstlane((b << 10) + (ny << 5) + nx);
        const float* sp = seeds + (size_t)si * NC;  // uniform -> s_load
        float ip = 0.f;
#pragma unroll
        for (int c = 0; c < NC; ++c) ip += xv[c] * sp[c];
        d[o] = snorm[si] - 2.0f * ip;
    }
    float m = d[0];
#pragma unroll
    for (int o = 1; o < 9; ++o) m = fminf(m, d[o]);
    float w[9];
    float wsum = 0.f;
#pragma unroll
    for (int o = 0; o < 9; ++o) {
        w[o] = __expf(m - d[o]);
        wsum += w[o];
    }
    const float inv = 1.0f / wsum;
#pragma unroll
    for (int o = 0; o < 9; ++o) {
        out[(((size_t)b * 9 + o) * NH + py) * NW + px] = w[o] * inv;
    }
}

// ---------------------------------------------------------------------------
extern "C" void kernel_launch(void* const* d_in, const int* in_sizes, int n_in,
                              void* d_out, int out_size, void* d_ws, size_t ws_size,
                              hipStream_t stream) {
    const float* x = (const float*)d_in[0];
    float* out = (float*)d_out;

    float* seeds = (float*)d_ws;                 // 163840 floats
    float* numer = seeds + SEEDS_ELEMS;          // 163840 floats
    float* denom = numer + SEEDS_ELEMS;          // 8192 floats
    float* snorm = denom + DENOM_ELEMS;          // 8192 floats

    // one-time zero of the accumulators (k_divz re-zeros between iterations)
    hipMemsetAsync(numer, 0, (SEEDS_ELEMS + DENOM_ELEMS) * sizeof(float), stream);

    const dim3 grid(NS, NB);  // 1024 cells x 8 batches
    k_seed_init<<<grid, 160, 0, stream>>>(x, seeds, snorm);

    for (int it = 0; it < 3; ++it) {
        k_iter<<<grid, 256, 0, stream>>>(x, seeds, snorm, numer, denom);
        k_divz<<<SEEDS_ELEMS / 160, 160, 0, stream>>>(seeds, snorm, numer, denom);
    }
    k_final<<<grid, 256, 0, stream>>>(x, seeds, snorm, out);
}